// Round 5
// baseline (428.339 us; speedup 1.0000x reference)
//
#include <hip/hip_runtime.h>

#define B_      8
#define DIM_    256
#define SEQ_    16384
#define K_      3
#define HID_    85          // DIM // 3
#define EPS_    1e-5f

typedef float floatx4 __attribute__((ext_vector_type(4)));

// ===========================================================================
// Cooperative fused kernel: 1024 blocks, each owns rows (2i, 2i+1) — same
// batch. Phases: pool both rows -> fence+atomicAdd(cnt[b],2) -> spin until
// cnt[b]==256 -> redundant per-block MLP -> 3-tap conv on both rows.
// __launch_bounds__(256,4): needs only 4 blocks/CU co-resident (VGPR<=128),
// giving the cooperative-launch validator a 2x margin vs the R4 failure.
// ===========================================================================
__global__ __launch_bounds__(256, 4) void fused_kernel(
        const float* __restrict__ x,
        const float* __restrict__ w1,
        const float* __restrict__ gamma,
        const float* __restrict__ beta,
        const float* __restrict__ mean,
        const float* __restrict__ var,
        const float* __restrict__ w2,
        const float* __restrict__ b2,
        const float* __restrict__ bias,
        float* __restrict__ pooled,
        int* __restrict__ cnt,
        float* __restrict__ out) {
    const int r0 = blockIdx.x * 2;                    // rows r0, r0+1
    const int b = r0 >> 8;
    const int c0 = r0 & (DIM_ - 1);
    const int lane = threadIdx.x & 63, wid = threadIdx.x >> 6;

    const float* xr0 = x + (size_t)r0 * SEQ_;
    const float* xr1 = xr0 + SEQ_;
    const floatx4* x40 = (const floatx4*)xr0;
    const floatx4* x41 = (const floatx4*)xr1;

    // ---- phase 1: pool both rows ----------------------------------------
    float s0 = 0.f, s1 = 0.f;
#pragma unroll 4
    for (int k = 0; k < SEQ_ / 4 / 256; ++k) {        // 16 iters per row
        floatx4 v0 = x40[threadIdx.x + k * 256];
        floatx4 v1 = x41[threadIdx.x + k * 256];
        s0 += (v0.x + v0.y) + (v0.z + v0.w);
        s1 += (v1.x + v1.y) + (v1.z + v1.w);
    }
#pragma unroll
    for (int off = 32; off > 0; off >>= 1) {
        s0 += __shfl_down(s0, off, 64);
        s1 += __shfl_down(s1, off, 64);
    }
    __shared__ float red0[4], red1[4];
    if (lane == 0) { red0[wid] = s0; red1[wid] = s1; }
    __syncthreads();
    if (threadIdx.x == 0) {
        pooled[r0]     = ((red0[0] + red0[1]) + (red0[2] + red0[3])) * (1.0f / SEQ_);
        pooled[r0 + 1] = ((red1[0] + red1[1]) + (red1[2] + red1[3])) * (1.0f / SEQ_);
        __threadfence();                               // release pooled
        atomicAdd(&cnt[b], 2);                         // device-scope
    }

    // ---- phase 2: wait for my batch -------------------------------------
    if (threadIdx.x == 0) {
        while (__hip_atomic_load(&cnt[b], __ATOMIC_ACQUIRE,
                                 __HIP_MEMORY_SCOPE_AGENT) < DIM_)
            __builtin_amdgcn_s_sleep(2);
    }
    __syncthreads();

    // ---- phase 3: MLP (redundant per block; tiny) ------------------------
    __shared__ float sp[DIM_];
    __shared__ float sy[HID_];
    sp[threadIdx.x] = __hip_atomic_load(&pooled[b * DIM_ + threadIdx.x],
                                        __ATOMIC_RELAXED, __HIP_MEMORY_SCOPE_AGENT);
    __syncthreads();
    if (threadIdx.x < HID_) {
        const int h = threadIdx.x;
        const float* w1r = w1 + h * DIM_;
        float acc = 0.f;
#pragma unroll 4
        for (int cc = 0; cc < DIM_; ++cc) acc = fmaf(sp[cc], w1r[cc], acc);
        float t = (acc - mean[h]) * (gamma[h] * rsqrtf(var[h] + EPS_)) + beta[h];
        sy[h] = fmaxf(t, 0.f);
    }
    __syncthreads();

    // taps for both channels (uniform addresses)
    float wa0 = b2[c0 * 3 + 0], wa1 = b2[c0 * 3 + 1], wa2 = b2[c0 * 3 + 2];
    float wb0 = b2[c0 * 3 + 3], wb1 = b2[c0 * 3 + 4], wb2 = b2[c0 * 3 + 5];
    {
        const float* w2r = w2 + c0 * 3 * HID_;
        for (int h = 0; h < HID_; ++h) {
            const float yv = sy[h];
            wa0 = fmaf(yv, w2r[0 * HID_ + h], wa0);
            wa1 = fmaf(yv, w2r[1 * HID_ + h], wa1);
            wa2 = fmaf(yv, w2r[2 * HID_ + h], wa2);
            wb0 = fmaf(yv, w2r[3 * HID_ + h], wb0);
            wb1 = fmaf(yv, w2r[4 * HID_ + h], wb1);
            wb2 = fmaf(yv, w2r[5 * HID_ + h], wb2);
        }
    }
    const float bsa = bias[c0], bsb = bias[c0 + 1];

    // ---- phase 4: conv both rows ----------------------------------------
    floatx4* o40 = (floatx4*)(out + (size_t)r0 * SEQ_);
    floatx4* o41 = o40 + SEQ_ / 4;
#pragma unroll 4
    for (int k = 0; k < SEQ_ / 4 / 256; ++k) {        // 16 iters
        const int j = threadIdx.x + k * 256;
        const int s0i = j * 4;
        floatx4 v0 = x40[j];
        floatx4 v1 = x41[j];
        float l0 = __shfl_up(v0.w, 1, 64),  l1 = __shfl_up(v1.w, 1, 64);
        float r0e = __shfl_down(v0.x, 1, 64), r1e = __shfl_down(v1.x, 1, 64);
        if (lane == 0) {
            l0 = (s0i > 0) ? xr0[s0i - 1] : 0.f;
            l1 = (s0i > 0) ? xr1[s0i - 1] : 0.f;
        }
        if (lane == 63) {
            r0e = (s0i + 4 < SEQ_) ? xr0[s0i + 4] : 0.f;
            r1e = (s0i + 4 < SEQ_) ? xr1[s0i + 4] : 0.f;
        }
        floatx4 q0, q1;
        q0.x = fmaf(wa0, l0,   fmaf(wa1, v0.x, wa2 * v0.y)) + bsa;
        q0.y = fmaf(wa0, v0.x, fmaf(wa1, v0.y, wa2 * v0.z)) + bsa;
        q0.z = fmaf(wa0, v0.y, fmaf(wa1, v0.z, wa2 * v0.w)) + bsa;
        q0.w = fmaf(wa0, v0.z, fmaf(wa1, v0.w, wa2 * r0e)) + bsa;
        q1.x = fmaf(wb0, l1,   fmaf(wb1, v1.x, wb2 * v1.y)) + bsb;
        q1.y = fmaf(wb0, v1.x, fmaf(wb1, v1.y, wb2 * v1.z)) + bsb;
        q1.z = fmaf(wb0, v1.y, fmaf(wb1, v1.z, wb2 * v1.w)) + bsb;
        q1.w = fmaf(wb0, v1.z, fmaf(wb1, v1.w, wb2 * r1e)) + bsb;
        __builtin_nontemporal_store(q0, &o40[j]);
        __builtin_nontemporal_store(q1, &o41[j]);
    }
}

// ===========================================================================
// Fallback path (proven R3 structure, 292 us): pool kernel + fused MLP+conv.
// ===========================================================================
__global__ __launch_bounds__(256) void pool_kernel(const float* __restrict__ x,
                                                   float* __restrict__ pooled) {
    const int row = blockIdx.x;
    const floatx4* x4 = (const floatx4*)(x + (size_t)row * SEQ_);
    float s = 0.f;
#pragma unroll
    for (int k = 0; k < SEQ_ / 4 / 256; ++k) {
        floatx4 v = x4[threadIdx.x + k * 256];
        s += (v.x + v.y) + (v.z + v.w);
    }
#pragma unroll
    for (int off = 32; off > 0; off >>= 1) s += __shfl_down(s, off, 64);
    __shared__ float lds[4];
    const int lane = threadIdx.x & 63, wid = threadIdx.x >> 6;
    if (lane == 0) lds[wid] = s;
    __syncthreads();
    if (threadIdx.x == 0)
        pooled[row] = ((lds[0] + lds[1]) + (lds[2] + lds[3])) * (1.0f / SEQ_);
}

__global__ __launch_bounds__(256) void conv_kernel(const float* __restrict__ x,
                                                   const float* __restrict__ pooled,
                                                   const float* __restrict__ w1,
                                                   const float* __restrict__ gamma,
                                                   const float* __restrict__ beta,
                                                   const float* __restrict__ mean,
                                                   const float* __restrict__ var,
                                                   const float* __restrict__ w2,
                                                   const float* __restrict__ b2,
                                                   const float* __restrict__ bias,
                                                   float* __restrict__ out) {
    const int row = blockIdx.x;
    const int b = row >> 8;
    const int c = row & (DIM_ - 1);
    __shared__ float sp[DIM_];
    __shared__ float sy[HID_];
    sp[threadIdx.x] = pooled[b * DIM_ + threadIdx.x];
    __syncthreads();
    if (threadIdx.x < HID_) {
        const int h = threadIdx.x;
        const float* w1r = w1 + h * DIM_;
        float acc = 0.f;
#pragma unroll 8
        for (int cc = 0; cc < DIM_; ++cc) acc = fmaf(sp[cc], w1r[cc], acc);
        float t = (acc - mean[h]) * (gamma[h] * rsqrtf(var[h] + EPS_)) + beta[h];
        sy[h] = fmaxf(t, 0.f);
    }
    __syncthreads();
    const float* w2r0 = w2 + (c * 3 + 0) * HID_;
    const float* w2r1 = w2 + (c * 3 + 1) * HID_;
    const float* w2r2 = w2 + (c * 3 + 2) * HID_;
    float w0 = b2[c * 3 + 0], w1t = b2[c * 3 + 1], w2t = b2[c * 3 + 2];
    for (int h = 0; h < HID_; ++h) {
        const float yv = sy[h];
        w0  = fmaf(yv, w2r0[h], w0);
        w1t = fmaf(yv, w2r1[h], w1t);
        w2t = fmaf(yv, w2r2[h], w2t);
    }
    const float bs = bias[c];
    const float* xr = x + (size_t)row * SEQ_;
    const floatx4* x4 = (const floatx4*)xr;
    floatx4* o4 = (floatx4*)(out + (size_t)row * SEQ_);
    const int lane = threadIdx.x & 63;
#pragma unroll
    for (int k = 0; k < SEQ_ / 4 / 256; ++k) {
        const int j = threadIdx.x + k * 256;
        const int s0 = j * 4;
        floatx4 v = x4[j];
        float left  = __shfl_up(v.w, 1, 64);
        float right = __shfl_down(v.x, 1, 64);
        if (lane == 0)  left  = (s0 > 0)        ? xr[s0 - 1] : 0.f;
        if (lane == 63) right = (s0 + 4 < SEQ_) ? xr[s0 + 4] : 0.f;
        floatx4 r;
        r.x = fmaf(w0, left, fmaf(w1t, v.x, w2t * v.y)) + bs;
        r.y = fmaf(w0, v.x,  fmaf(w1t, v.y, w2t * v.z)) + bs;
        r.z = fmaf(w0, v.y,  fmaf(w1t, v.z, w2t * v.w)) + bs;
        r.w = fmaf(w0, v.z,  fmaf(w1t, v.w, w2t * right)) + bs;
        __builtin_nontemporal_store(r, &o4[j]);
    }
}

// ---------------------------------------------------------------------------
extern "C" void kernel_launch(void* const* d_in, const int* in_sizes, int n_in,
                              void* d_out, int out_size, void* d_ws, size_t ws_size,
                              hipStream_t stream) {
    const float* x     = (const float*)d_in[0];
    const float* w1    = (const float*)d_in[1];
    const float* gamma = (const float*)d_in[2];
    const float* beta  = (const float*)d_in[3];
    const float* mean  = (const float*)d_in[4];
    const float* var   = (const float*)d_in[5];
    const float* w2    = (const float*)d_in[6];
    const float* b2    = (const float*)d_in[7];
    const float* bias  = (const float*)d_in[8];
    float* out = (float*)d_out;

    int*   cnt    = (int*)d_ws;                     // 8 ints
    float* pooled = (float*)d_ws + 16;              // B*DIM floats

    hipMemsetAsync(cnt, 0, B_ * sizeof(int), stream);

    void* args[] = { (void*)&x, (void*)&w1, (void*)&gamma, (void*)&beta,
                     (void*)&mean, (void*)&var, (void*)&w2, (void*)&b2,
                     (void*)&bias, (void*)&pooled, (void*)&cnt, (void*)&out };
    hipError_t e = hipLaunchCooperativeKernel((const void*)fused_kernel,
                                              dim3(B_ * DIM_ / 2), dim3(256),
                                              args, 0, stream);
    if (e != hipSuccess) {
        // deterministic fallback: proven two-kernel path
        pool_kernel<<<B_ * DIM_, 256, 0, stream>>>(x, pooled);
        conv_kernel<<<B_ * DIM_, 256, 0, stream>>>(x, pooled, w1, gamma, beta,
                                                   mean, var, w2, b2, bias, out);
    }
}